// Round 8
// baseline (891.236 us; speedup 1.0000x reference)
//
#include <hip/hip_runtime.h>

// GCNEncoder: h1 = x@W1; hag = relu(A_norm h1 + b1); h2 = hag@W2; out = A_norm h2 + b2
// A_norm (self loops): out[v] = dinv[v]^2 h[v] + sum_{e:dst=v} dinv[src]dinv[v] h[src]
// Established: float inputs f32 (probed), edges int64 (probed), output f32.
// h1/hag/h2 bf16. GEMMs = MFMA 16x16x32.
// R8: per-node CSR dropped. Edges only bucket-sorted (128 nodes/bucket) by
// hist -> hscan -> stage2 (all LDS-atomic / atomic-free). Aggregation is
// bucket-per-block with LDS f32 accumulators + ds_add_f32 (col=lane -> 2
// lanes/bank = conflict-free). degree fused into hist. Removed: degree,
// scan x3, scatter (14 -> 10 dispatches).

#define GCN_IN 256
#define GCN_HID 128
#define GCN_OUT 64

#define BKT 128          // nodes per bucket (dst >> 7)
#define SBE 16384        // edges per superblock
#define SRCM 0x1FFFFFFu  // 25-bit src mask (N < 33.5M)

typedef unsigned short ushort_t;
typedef __attribute__((ext_vector_type(8))) short short8;     // 8 bf16 (4 VGPR)
typedef __attribute__((ext_vector_type(8))) unsigned short ushort8;
typedef __attribute__((ext_vector_type(4))) float f32x4;

__device__ inline float bf2f(ushort_t u) {
  union { unsigned int i; float f; } x; x.i = ((unsigned int)u) << 16; return x.f;
}
__device__ inline ushort_t f2bf(float f) {
  union { float f; unsigned int i; } u; u.f = f;
  unsigned int r = u.i + 0x7FFFu + ((u.i >> 16) & 1u);  // RNE
  return (ushort_t)(r >> 16);
}

// ---------------- dtype probe ----------------
// flags[0]: 1 = float inputs f32, 0 = bf16.  flags[1]: 1 = edges int64, 0 = int32.
__global__ void probe_kernel(const ushort_t* __restrict__ xu,
                             const int* __restrict__ ei,
                             int* __restrict__ flags) {
  int lane = threadIdx.x;  // 64 threads
  int c = 0, nz = 0;
  for (int i = lane; i < 128; i += 64) {
    ushort_t u = xu[2 * i];
    int e = (u >> 7) & 0xFF;
    c += (e >= 100 && e <= 140) ? 1 : 0;
    nz += (ei[2 * i + 1] != 0) ? 1 : 0;
  }
  for (int off = 32; off > 0; off >>= 1) {
    c += __shfl_down(c, off);
    nz += __shfl_down(nz, off);
  }
  if (lane == 0) {
    flags[0] = (c >= 64) ? 0 : 1;
    flags[1] = (nz == 0) ? 1 : 0;
  }
}

// ---- Pass A: per-superblock LDS bucket histogram + global per-node degree ----
__global__ void hist_kernel(const int* __restrict__ ei, int E,
                            int* __restrict__ Hmat, int nsb, int nbin,
                            int* __restrict__ degcnt,
                            const int* __restrict__ flags) {
  __shared__ int hist[256];
  int t = threadIdx.x;
  int sb = blockIdx.x;
  hist[t] = 0;
  __syncthreads();
  int base = sb * SBE;
  int end = base + SBE; if (end > E) end = E;
  bool i64 = flags[1] != 0;
  for (int i = base + t; i < end; i += 256) {
    int d = i64 ? ei[2 * E + 2 * i] : ei[E + i];
    atomicAdd(&hist[d >> 7], 1);            // LDS atomic
    atomicAdd(&degcnt[d], 1);               // global (120KB spread, parallel)
  }
  __syncthreads();
  for (int b = t; b < nbin; b += 256)
    Hmat[b * nsb + sb] = hist[b];
}

__global__ void dinv_kernel(const int* __restrict__ degcnt, float* __restrict__ dinv, int n) {
  int v = blockIdx.x * blockDim.x + threadIdx.x;
  if (v < n) dinv[v] = rsqrtf((float)(degcnt[v] + 1));  // +1 self loop
}

// ---- Pass B: one-block in-place exclusive scan of m = nbin*nsb (<16K) ints ----
__global__ void hscan_kernel(int* __restrict__ data, int m) {
  __shared__ int red[1024];
  int t = threadIdx.x;
  int per = (m + 1023) >> 10;               // <=16
  int start = t * per;
  int end = start + per; if (end > m) end = m;
  int vals[16];
  int s = 0;
  for (int i = start; i < end; ++i) { vals[i - start] = data[i]; s += vals[i - start]; }
  red[t] = s;
  __syncthreads();
  for (int off = 1; off < 1024; off <<= 1) {
    int u = (t >= off) ? red[t - off] : 0;
    __syncthreads();
    red[t] += u;
    __syncthreads();
  }
  int run = (t == 0) ? 0 : red[t - 1];
  for (int i = start; i < end; ++i) { data[i] = run; run += vals[i - start]; }
}

// ---- Pass C: stage edges bucket-sorted; LDS cursors seeded from scanned Hmat.
// Packed u32: src (25b) | dst_local (7b) << 25.
__global__ void stage2_kernel(const int* __restrict__ ei, int E,
                              const int* __restrict__ Hscan, int nsb, int nbin,
                              unsigned int* __restrict__ stage,
                              const int* __restrict__ flags) {
  __shared__ int cur[256];
  int t = threadIdx.x;
  int sb = blockIdx.x;
  for (int b = t; b < nbin; b += 256)
    cur[b] = Hscan[b * nsb + sb];
  __syncthreads();
  int base = sb * SBE;
  int end = base + SBE; if (end > E) end = E;
  bool i64 = flags[1] != 0;
  for (int i = base + t; i < end; i += 256) {
    int s, d;
    if (i64) { s = ei[2 * i]; d = ei[2 * E + 2 * i]; }
    else     { s = ei[i];     d = ei[E + i]; }
    int pos = atomicAdd(&cur[d >> 7], 1);   // LDS atomic
    stage[pos] = (unsigned int)s | ((unsigned int)(d & 127) << 25);
  }
}

// ---------------- weight prep: transpose + bf16 (Wt[n][k]) ----------------
__global__ void prep_w_kernel(const void* __restrict__ W1, const void* __restrict__ W2,
                              ushort_t* __restrict__ Wt1, ushort_t* __restrict__ Wt2,
                              const int* __restrict__ flags) {
  int i = blockIdx.x * blockDim.x + threadIdx.x;
  bool f32 = flags[0] != 0;
  if (i < GCN_IN * GCN_HID) {                 // W1[k][n]
    int k = i >> 7, n = i & 127;
    float v = f32 ? ((const float*)W1)[i] : bf2f(((const ushort_t*)W1)[i]);
    Wt1[n * GCN_IN + k] = f2bf(v);
  }
  int j = i - GCN_IN * GCN_HID;
  if (j >= 0 && j < GCN_HID * GCN_OUT) {      // W2[k][n]
    int k = j >> 6, n = j & 63;
    float v = f32 ? ((const float*)W2)[j] : bf2f(((const ushort_t*)W2)[j]);
    Wt2[n * GCN_HID + k] = f2bf(v);
  }
}

// ---------------- MFMA GEMM: C[M,NC] = A[M,K] @ Bt[NC,K]^T, bf16 in/out ----------------
template<int K, int NC, int A_MODE>
__global__ __launch_bounds__(256)
void gemm_mfma_kernel(const void* __restrict__ A, const ushort_t* __restrict__ Bt,
                      ushort_t* __restrict__ C, int M, const int* __restrict__ flags) {
  constexpr int KT = 32;
  constexpr int NT = NC / 32;
  __shared__ ushort_t As[32 * KT];
  __shared__ ushort_t Bs[NC * KT];
  const int tid = threadIdx.x;
  const int wv = tid >> 6;
  const int lane = tid & 63;
  const int ml = lane & 15;
  const int quad = lane >> 4;
  const int row0 = blockIdx.x * 32;
  const int mrow = (wv & 1) * 16 + ml;
  const int ncol0 = (wv >> 1) * (NC / 2);
  const bool aF32 = (A_MODE == 0) && (flags[0] != 0);
  f32x4 acc[NT] = {};

  for (int kt = 0; kt < K; kt += KT) {
    for (int c = tid; c < 32 * KT / 8; c += 256) {
      int r = c >> 2, cq = c & 3;
      ushort8 o;
      if (row0 + r < M) {
        if (aF32) {
          const float* ap = (const float*)A + (size_t)(row0 + r) * K + kt + cq * 8;
          float4 f0 = *(const float4*)ap;
          float4 f1 = *(const float4*)(ap + 4);
          o[0] = f2bf(f0.x); o[1] = f2bf(f0.y); o[2] = f2bf(f0.z); o[3] = f2bf(f0.w);
          o[4] = f2bf(f1.x); o[5] = f2bf(f1.y); o[6] = f2bf(f1.z); o[7] = f2bf(f1.w);
        } else {
          o = *(const ushort8*)((const ushort_t*)A + (size_t)(row0 + r) * K + kt + cq * 8);
        }
      } else {
        o = (ushort8)0;
      }
      *(ushort8*)&As[c * 8] = o;
    }
    for (int c = tid; c < NC * KT / 8; c += 256) {
      int n = c >> 2, cq = c & 3;
      *(ushort8*)&Bs[c * 8] = *(const ushort8*)(Bt + (size_t)n * K + kt + cq * 8);
    }
    __syncthreads();
    short8 af = *(const short8*)&As[mrow * KT + quad * 8];
#pragma unroll
    for (int t = 0; t < NT; ++t) {
      short8 bf = *(const short8*)&Bs[(ncol0 + t * 16 + ml) * KT + quad * 8];
      acc[t] = __builtin_amdgcn_mfma_f32_16x16x32_bf16(af, bf, acc[t], 0, 0, 0);
    }
    __syncthreads();
  }

  const int orow = row0 + (wv & 1) * 16 + quad * 4;
#pragma unroll
  for (int t = 0; t < NT; ++t) {
    int col = ncol0 + t * 16 + ml;
#pragma unroll
    for (int r = 0; r < 4; ++r) {
      if (orow + r < M)
        C[(size_t)(orow + r) * NC + col] = f2bf(acc[t][r]);
    }
  }
}

// ---------------- bucket aggregation: block per 128-node bucket ----------------
// LDS f32 acc rows (pad +4: atomic col=lane -> bank (4r+lane)%32, 2 lanes/bank = free).
// Init: dinv[v]^2 * h[v]. Per edge: wave gathers src row, ds_add_f32 into dst row.

__global__ __launch_bounds__(512)
void agg1_kernel(const ushort_t* __restrict__ h,
                 const unsigned int* __restrict__ stage,
                 const int* __restrict__ Hmat, int nsb, int nbin,
                 const float* __restrict__ dinv,
                 const void* __restrict__ bias,
                 ushort_t* __restrict__ outp, int n, int E,
                 const int* __restrict__ flags) {
  __shared__ float acc[BKT][GCN_HID + 4];
  __shared__ float dloc[BKT];
  const int tid = threadIdx.x;
  const int b = blockIdx.x;
  const int node0 = b * BKT;
  const int nn = (n - node0 < BKT) ? (n - node0) : BKT;
  if (tid < BKT) dloc[tid] = (tid < nn) ? dinv[node0 + tid] : 0.f;
  __syncthreads();
  for (int i = tid; i < BKT * (GCN_HID / 8); i += 512) {
    int r = i >> 4, c8 = (i & 15) * 8;
    float4 v0 = make_float4(0.f, 0.f, 0.f, 0.f), v1 = v0;
    if (r < nn) {
      ushort8 g = *(const ushort8*)(h + (size_t)(node0 + r) * GCN_HID + c8);
      float sl = dloc[r] * dloc[r];
      v0 = make_float4(sl * bf2f(g[0]), sl * bf2f(g[1]), sl * bf2f(g[2]), sl * bf2f(g[3]));
      v1 = make_float4(sl * bf2f(g[4]), sl * bf2f(g[5]), sl * bf2f(g[6]), sl * bf2f(g[7]));
    }
    *(float4*)&acc[r][c8] = v0;
    *(float4*)&acc[r][c8 + 4] = v1;
  }
  __syncthreads();
  const int rb = Hmat[b * nsb];
  const int re = (b + 1 < nbin) ? Hmat[(b + 1) * nsb] : E;
  const int wv = tid >> 6, lane = tid & 63;
  for (int base = rb + wv * 64; base < re; base += 512) {
    int cnt = re - base; if (cnt > 64) cnt = 64;
    unsigned int pk = 0; float dvv = 0.f;
    if (base + lane < re) { pk = stage[base + lane]; dvv = dinv[pk & SRCM]; }
    int j = 0;
    for (; j + 4 <= cnt; j += 4) {
      unsigned int p0 = __shfl(pk, j),     p1 = __shfl(pk, j + 1);
      unsigned int p2 = __shfl(pk, j + 2), p3 = __shfl(pk, j + 3);
      float d0 = __shfl(dvv, j),     d1 = __shfl(dvv, j + 1);
      float d2 = __shfl(dvv, j + 2), d3 = __shfl(dvv, j + 3);
      int s0 = p0 & SRCM, l0 = p0 >> 25; float n0 = d0 * dloc[l0];
      int s1 = p1 & SRCM, l1 = p1 >> 25; float n1 = d1 * dloc[l1];
      int s2 = p2 & SRCM, l2 = p2 >> 25; float n2 = d2 * dloc[l2];
      int s3 = p3 & SRCM, l3 = p3 >> 25; float n3 = d3 * dloc[l3];
      float a0 = bf2f(h[(size_t)s0 * GCN_HID + lane]);
      float b0 = bf2f(h[(size_t)s0 * GCN_HID + 64 + lane]);
      float a1 = bf2f(h[(size_t)s1 * GCN_HID + lane]);
      float b1v = bf2f(h[(size_t)s1 * GCN_HID + 64 + lane]);
      float a2 = bf2f(h[(size_t)s2 * GCN_HID + lane]);
      float b2v = bf2f(h[(size_t)s2 * GCN_HID + 64 + lane]);
      float a3 = bf2f(h[(size_t)s3 * GCN_HID + lane]);
      float b3v = bf2f(h[(size_t)s3 * GCN_HID + 64 + lane]);
      atomicAdd(&acc[l0][lane], n0 * a0); atomicAdd(&acc[l0][64 + lane], n0 * b0);
      atomicAdd(&acc[l1][lane], n1 * a1); atomicAdd(&acc[l1][64 + lane], n1 * b1v);
      atomicAdd(&acc[l2][lane], n2 * a2); atomicAdd(&acc[l2][64 + lane], n2 * b2v);
      atomicAdd(&acc[l3][lane], n3 * a3); atomicAdd(&acc[l3][64 + lane], n3 * b3v);
    }
    for (; j < cnt; ++j) {
      unsigned int p = __shfl(pk, j);
      float dv = __shfl(dvv, j);
      int s = p & SRCM, l = p >> 25; float nrm = dv * dloc[l];
      float a = bf2f(h[(size_t)s * GCN_HID + lane]);
      float bb = bf2f(h[(size_t)s * GCN_HID + 64 + lane]);
      atomicAdd(&acc[l][lane], nrm * a); atomicAdd(&acc[l][64 + lane], nrm * bb);
    }
  }
  __syncthreads();
  const bool bF32 = flags[0] != 0;
  for (int i = tid; i < BKT * (GCN_HID / 8); i += 512) {
    int r = i >> 4, c8 = (i & 15) * 8;
    if (r >= nn) continue;
    ushort8 o;
#pragma unroll
    for (int jj = 0; jj < 8; ++jj) {
      float bv = bF32 ? ((const float*)bias)[c8 + jj]
                      : bf2f(((const ushort_t*)bias)[c8 + jj]);
      o[jj] = f2bf(fmaxf(acc[r][c8 + jj] + bv, 0.f));
    }
    *(ushort8*)(outp + (size_t)(node0 + r) * GCN_HID + c8) = o;
  }
}

__global__ __launch_bounds__(512)
void agg2_kernel(const ushort_t* __restrict__ h,
                 const unsigned int* __restrict__ stage,
                 const int* __restrict__ Hmat, int nsb, int nbin,
                 const float* __restrict__ dinv,
                 const void* __restrict__ bias,
                 void* __restrict__ outp, int n, int E,
                 const int* __restrict__ flags) {
  __shared__ float acc[BKT][GCN_OUT + 4];
  __shared__ float dloc[BKT];
  const int tid = threadIdx.x;
  const int b = blockIdx.x;
  const int node0 = b * BKT;
  const int nn = (n - node0 < BKT) ? (n - node0) : BKT;
  if (tid < BKT) dloc[tid] = (tid < nn) ? dinv[node0 + tid] : 0.f;
  __syncthreads();
  for (int i = tid; i < BKT * (GCN_OUT / 8); i += 512) {
    int r = i >> 3, c8 = (i & 7) * 8;
    float4 v0 = make_float4(0.f, 0.f, 0.f, 0.f), v1 = v0;
    if (r < nn) {
      ushort8 g = *(const ushort8*)(h + (size_t)(node0 + r) * GCN_OUT + c8);
      float sl = dloc[r] * dloc[r];
      v0 = make_float4(sl * bf2f(g[0]), sl * bf2f(g[1]), sl * bf2f(g[2]), sl * bf2f(g[3]));
      v1 = make_float4(sl * bf2f(g[4]), sl * bf2f(g[5]), sl * bf2f(g[6]), sl * bf2f(g[7]));
    }
    *(float4*)&acc[r][c8] = v0;
    *(float4*)&acc[r][c8 + 4] = v1;
  }
  __syncthreads();
  const int rb = Hmat[b * nsb];
  const int re = (b + 1 < nbin) ? Hmat[(b + 1) * nsb] : E;
  const int wv = tid >> 6, lane = tid & 63;
  for (int base = rb + wv * 64; base < re; base += 512) {
    int cnt = re - base; if (cnt > 64) cnt = 64;
    unsigned int pk = 0; float dvv = 0.f;
    if (base + lane < re) { pk = stage[base + lane]; dvv = dinv[pk & SRCM]; }
    int j = 0;
    for (; j + 4 <= cnt; j += 4) {
      unsigned int p0 = __shfl(pk, j),     p1 = __shfl(pk, j + 1);
      unsigned int p2 = __shfl(pk, j + 2), p3 = __shfl(pk, j + 3);
      float d0 = __shfl(dvv, j),     d1 = __shfl(dvv, j + 1);
      float d2 = __shfl(dvv, j + 2), d3 = __shfl(dvv, j + 3);
      int s0 = p0 & SRCM, l0 = p0 >> 25; float n0 = d0 * dloc[l0];
      int s1 = p1 & SRCM, l1 = p1 >> 25; float n1 = d1 * dloc[l1];
      int s2 = p2 & SRCM, l2 = p2 >> 25; float n2 = d2 * dloc[l2];
      int s3 = p3 & SRCM, l3 = p3 >> 25; float n3 = d3 * dloc[l3];
      float g0 = bf2f(h[(size_t)s0 * GCN_OUT + lane]);
      float g1 = bf2f(h[(size_t)s1 * GCN_OUT + lane]);
      float g2 = bf2f(h[(size_t)s2 * GCN_OUT + lane]);
      float g3 = bf2f(h[(size_t)s3 * GCN_OUT + lane]);
      atomicAdd(&acc[l0][lane], n0 * g0);
      atomicAdd(&acc[l1][lane], n1 * g1);
      atomicAdd(&acc[l2][lane], n2 * g2);
      atomicAdd(&acc[l3][lane], n3 * g3);
    }
    for (; j < cnt; ++j) {
      unsigned int p = __shfl(pk, j);
      float dv = __shfl(dvv, j);
      int s = p & SRCM, l = p >> 25; float nrm = dv * dloc[l];
      atomicAdd(&acc[l][lane], nrm * bf2f(h[(size_t)s * GCN_OUT + lane]));
    }
  }
  __syncthreads();
  const bool oF32 = flags[0] != 0;
  for (int i = tid; i < BKT * (GCN_OUT / 8); i += 512) {
    int r = i >> 3, c8 = (i & 7) * 8;
    if (r >= nn) continue;
    float v[8];
#pragma unroll
    for (int jj = 0; jj < 8; ++jj) {
      float bv = oF32 ? ((const float*)bias)[c8 + jj]
                      : bf2f(((const ushort_t*)bias)[c8 + jj]);
      v[jj] = acc[r][c8 + jj] + bv;
    }
    if (oF32) {
      float* op = (float*)outp + (size_t)(node0 + r) * GCN_OUT + c8;
      *(float4*)op = make_float4(v[0], v[1], v[2], v[3]);
      *(float4*)(op + 4) = make_float4(v[4], v[5], v[6], v[7]);
    } else {
      ushort8 o;
#pragma unroll
      for (int jj = 0; jj < 8; ++jj) o[jj] = f2bf(v[jj]);
      *(ushort8*)((ushort_t*)outp + (size_t)(node0 + r) * GCN_OUT + c8) = o;
    }
  }
}

// ---------------- launch ----------------

extern "C" void kernel_launch(void* const* d_in, const int* in_sizes, int n_in,
                              void* d_out, int out_size, void* d_ws, size_t ws_size,
                              hipStream_t stream) {
  const void* x  = d_in[0];               // [N, 256] f32 (probed)
  const int*  ei = (const int*)d_in[1];   // [2, E] int32/int64 (probed)
  const void* W1 = d_in[2];               // [256,128]
  const void* b1 = d_in[3];               // [128]
  const void* W2 = d_in[4];               // [128,64]
  const void* b2 = d_in[5];               // [64]

  const int N = in_sizes[0] / GCN_IN;     // 30000
  const int E = in_sizes[1] / 2;          // 600000
  const int nsb  = (E + SBE - 1) / SBE;   // 37 superblocks
  const int nbin = (N + BKT - 1) / BKT;   // 235 buckets (<=256 for LDS hist)

  size_t off = 0;
  auto alloc = [&](size_t bytes) -> void* {
    void* p = (char*)d_ws + off;
    off += (bytes + 255) & ~(size_t)255;
    return p;
  };
  int*          flags  = (int*)alloc(256);
  int*          degcnt = (int*)alloc((size_t)N * 4);
  float*        dinv   = (float*)alloc((size_t)N * 4);
  int*          Hmat   = (int*)alloc((size_t)nbin * nsb * 4);
  unsigned int* stage  = (unsigned int*)alloc((size_t)E * 4);
  ushort_t*     h1     = (ushort_t*)alloc((size_t)N * GCN_HID * 2);  // bf16
  ushort_t*     hag    = (ushort_t*)alloc((size_t)N * GCN_HID * 2);  // bf16
  ushort_t*     wt1    = (ushort_t*)alloc((size_t)GCN_HID * GCN_IN * 2);
  ushort_t*     wt2    = (ushort_t*)alloc((size_t)GCN_OUT * GCN_HID * 2);
  ushort_t*     h2     = h1;  // h1 dead after hag; reuse for GEMM2 output

  hipMemsetAsync(degcnt, 0, (size_t)N * 4, stream);
  probe_kernel<<<1, 64, 0, stream>>>((const ushort_t*)x, ei, flags);

  hist_kernel<<<nsb, 256, 0, stream>>>(ei, E, Hmat, nsb, nbin, degcnt, flags);
  dinv_kernel<<<(N + 255) / 256, 256, 0, stream>>>(degcnt, dinv, N);
  hscan_kernel<<<1, 1024, 0, stream>>>(Hmat, nbin * nsb);
  stage2_kernel<<<nsb, 256, 0, stream>>>(ei, E, Hmat, nsb, nbin, stage, flags);

  prep_w_kernel<<<(GCN_IN * GCN_HID + GCN_HID * GCN_OUT + 255) / 256, 256, 0, stream>>>(
      W1, W2, wt1, wt2, flags);

  // GEMM1: [N,256] @ [256,128] -> h1 bf16 (MFMA)
  gemm_mfma_kernel<GCN_IN, GCN_HID, 0>
      <<<(N + 31) / 32, 256, 0, stream>>>(x, wt1, h1, N, flags);

  agg1_kernel<<<nbin, 512, 0, stream>>>(h1, stage, Hmat, nsb, nbin, dinv, b1,
                                        hag, N, E, flags);

  // GEMM2: [N,128] @ [128,64] -> h2 bf16 (MFMA, A bf16)
  gemm_mfma_kernel<GCN_HID, GCN_OUT, 2>
      <<<(N + 31) / 32, 256, 0, stream>>>(hag, wt2, h2, N, flags);

  agg2_kernel<<<nbin, 512, 0, stream>>>(h2, stage, Hmat, nsb, nbin, dinv, b2,
                                        d_out, N, E, flags);
}

// Round 9
// 201.781 us; speedup vs baseline: 4.4169x; 4.4169x over previous
//
#include <hip/hip_runtime.h>

// GCNEncoder: h1 = x@W1; hag = relu(A_norm h1 + b1); h2 = hag@W2; out = A_norm h2 + b2
// A_norm (self loops): out[v] = dinv[v]^2 h[v] + sum_{e:dst=v} dinv[src]dinv[v] h[src]
// Established: float inputs f32 (probed), edges int64 (probed), output f32.
// h1/hag/h2 bf16. GEMMs = MFMA 16x16x32.
// R9: R8's bucket-LDS-atomic aggregation was 472us (1880 waves of TLP vs R7's
// 30000; LDS-atomic+gather dependency chain uncovered). REVERTED to R7's
// wave-per-node CSR aggregation (proven). Kept counting-sort CSR build, now
// leaner: scatter_kernel derives row_ptr/dinv/cursors LOCALLY per bucket
// (local hist + 128-wide LDS scan) — degree, memset, dinv, 3-pass scan,
// global cursor all deleted. 10 dispatches.

#define GCN_IN 256
#define GCN_HID 128
#define GCN_OUT 64

#define BKT 128          // nodes per bucket (dst >> 7)
#define SBE 16384        // edges per superblock
#define SRCM 0x1FFFFFFu  // 25-bit src mask

typedef unsigned short ushort_t;
typedef __attribute__((ext_vector_type(8))) short short8;     // 8 bf16 (4 VGPR)
typedef __attribute__((ext_vector_type(8))) unsigned short ushort8;
typedef __attribute__((ext_vector_type(4))) float f32x4;

__device__ inline float bf2f(ushort_t u) {
  union { unsigned int i; float f; } x; x.i = ((unsigned int)u) << 16; return x.f;
}
__device__ inline ushort_t f2bf(float f) {
  union { float f; unsigned int i; } u; u.f = f;
  unsigned int r = u.i + 0x7FFFu + ((u.i >> 16) & 1u);  // RNE
  return (ushort_t)(r >> 16);
}

// ---------------- dtype probe ----------------
// flags[0]: 1 = float inputs f32, 0 = bf16.  flags[1]: 1 = edges int64, 0 = int32.
__global__ void probe_kernel(const ushort_t* __restrict__ xu,
                             const int* __restrict__ ei,
                             int* __restrict__ flags) {
  int lane = threadIdx.x;  // 64 threads
  int c = 0, nz = 0;
  for (int i = lane; i < 128; i += 64) {
    ushort_t u = xu[2 * i];
    int e = (u >> 7) & 0xFF;
    c += (e >= 100 && e <= 140) ? 1 : 0;
    nz += (ei[2 * i + 1] != 0) ? 1 : 0;
  }
  for (int off = 32; off > 0; off >>= 1) {
    c += __shfl_down(c, off);
    nz += __shfl_down(nz, off);
  }
  if (lane == 0) {
    flags[0] = (c >= 64) ? 0 : 1;
    flags[1] = (nz == 0) ? 1 : 0;
  }
}

// ---- Pass A: per-superblock LDS bucket histogram -> Hmat[bin*nsb+sb] ----
__global__ void hist_kernel(const int* __restrict__ ei, int E,
                            int* __restrict__ Hmat, int nsb, int nbin,
                            const int* __restrict__ flags) {
  __shared__ int hist[256];
  int t = threadIdx.x;
  int sb = blockIdx.x;
  hist[t] = 0;
  __syncthreads();
  int base = sb * SBE;
  int end = base + SBE; if (end > E) end = E;
  bool i64 = flags[1] != 0;
  for (int i = base + t; i < end; i += 256) {
    int d = i64 ? ei[2 * E + 2 * i] : ei[E + i];
    atomicAdd(&hist[d >> 7], 1);            // LDS atomic
  }
  __syncthreads();
  for (int b = t; b < nbin; b += 256)
    Hmat[b * nsb + sb] = hist[b];
}

// ---- Pass B: one-block in-place exclusive scan of m = nbin*nsb (<16K) ints ----
__global__ void hscan_kernel(int* __restrict__ data, int m) {
  __shared__ int red[1024];
  int t = threadIdx.x;
  int per = (m + 1023) >> 10;               // <=16
  int start = t * per;
  int end = start + per; if (end > m) end = m;
  int vals[16];
  int s = 0;
  for (int i = start; i < end; ++i) { vals[i - start] = data[i]; s += vals[i - start]; }
  red[t] = s;
  __syncthreads();
  for (int off = 1; off < 1024; off <<= 1) {
    int u = (t >= off) ? red[t - off] : 0;
    __syncthreads();
    red[t] += u;
    __syncthreads();
  }
  int run = (t == 0) ? 0 : red[t - 1];
  for (int i = start; i < end; ++i) { data[i] = run; run += vals[i - start]; }
}

// ---- Pass C: stage edges bucket-sorted; LDS cursors seeded from scanned Hmat.
// Packed u32: src (25b) | dst_local (7b) << 25.
__global__ void stage2_kernel(const int* __restrict__ ei, int E,
                              const int* __restrict__ Hscan, int nsb, int nbin,
                              unsigned int* __restrict__ stage,
                              const int* __restrict__ flags) {
  __shared__ int cur[256];
  int t = threadIdx.x;
  int sb = blockIdx.x;
  for (int b = t; b < nbin; b += 256)
    cur[b] = Hscan[b * nsb + sb];
  __syncthreads();
  int base = sb * SBE;
  int end = base + SBE; if (end > E) end = E;
  bool i64 = flags[1] != 0;
  for (int i = base + t; i < end; i += 256) {
    int s, d;
    if (i64) { s = ei[2 * i]; d = ei[2 * E + 2 * i]; }
    else     { s = ei[i];     d = ei[E + i]; }
    int pos = atomicAdd(&cur[d >> 7], 1);   // LDS atomic
    stage[pos] = (unsigned int)s | ((unsigned int)(d & 127) << 25);
  }
}

// ---- Pass D: block per bucket. Local hist -> local scan -> row_ptr + dinv +
// LDS cursors -> scatter csr_src within the bucket's contiguous window.
__global__ void scatter_kernel(const unsigned int* __restrict__ stage,
                               const int* __restrict__ Hmat, int nsb, int nbin,
                               int* __restrict__ csr_src,
                               int* __restrict__ row_ptr,
                               float* __restrict__ dinv, int n, int E) {
  __shared__ int lcnt[BKT];
  __shared__ int lscan[BKT];
  __shared__ int lcur[BKT];
  const int t = threadIdx.x;                // 256 threads
  const int b = blockIdx.x;
  const int node0 = b * BKT;
  const int nn = (n - node0 < BKT) ? (n - node0) : BKT;
  const int rb = Hmat[b * nsb];
  const int re = (b + 1 < nbin) ? Hmat[(b + 1) * nsb] : E;
  if (t < BKT) lcnt[t] = 0;
  __syncthreads();
  for (int i = rb + t; i < re; i += 256)
    atomicAdd(&lcnt[stage[i] >> 25], 1);    // LDS atomic, 128 counters
  __syncthreads();
  if (t < BKT) lscan[t] = lcnt[t];
  __syncthreads();
  for (int off = 1; off < BKT; off <<= 1) {  // Hillis-Steele inclusive scan
    int v = 0;
    if (t < BKT && t >= off) v = lscan[t - off];
    __syncthreads();
    if (t < BKT) lscan[t] += v;
    __syncthreads();
  }
  if (t < BKT) {
    int excl = rb + lscan[t] - lcnt[t];
    lcur[t] = excl;
    if (t < nn) {
      row_ptr[node0 + t] = excl;
      dinv[node0 + t] = rsqrtf((float)(lcnt[t] + 1));  // +1 self loop
    }
  }
  if (t == 0 && node0 + nn == n) row_ptr[n] = E;
  __syncthreads();
  for (int i = rb + t; i < re; i += 256) {
    unsigned int p = stage[i];
    int l = p >> 25;
    int pos = atomicAdd(&lcur[l], 1);       // LDS atomic cursor
    csr_src[pos] = (int)(p & SRCM);         // write within ~10KB L2-local window
  }
}

// ---------------- weight prep: transpose + bf16 (Wt[n][k]) ----------------
__global__ void prep_w_kernel(const void* __restrict__ W1, const void* __restrict__ W2,
                              ushort_t* __restrict__ Wt1, ushort_t* __restrict__ Wt2,
                              const int* __restrict__ flags) {
  int i = blockIdx.x * blockDim.x + threadIdx.x;
  bool f32 = flags[0] != 0;
  if (i < GCN_IN * GCN_HID) {                 // W1[k][n]
    int k = i >> 7, n = i & 127;
    float v = f32 ? ((const float*)W1)[i] : bf2f(((const ushort_t*)W1)[i]);
    Wt1[n * GCN_IN + k] = f2bf(v);
  }
  int j = i - GCN_IN * GCN_HID;
  if (j >= 0 && j < GCN_HID * GCN_OUT) {      // W2[k][n]
    int k = j >> 6, n = j & 63;
    float v = f32 ? ((const float*)W2)[j] : bf2f(((const ushort_t*)W2)[j]);
    Wt2[n * GCN_HID + k] = f2bf(v);
  }
}

// ---------------- MFMA GEMM: C[M,NC] = A[M,K] @ Bt[NC,K]^T, bf16 in/out ----------------
template<int K, int NC, int A_MODE>
__global__ __launch_bounds__(256)
void gemm_mfma_kernel(const void* __restrict__ A, const ushort_t* __restrict__ Bt,
                      ushort_t* __restrict__ C, int M, const int* __restrict__ flags) {
  constexpr int KT = 32;
  constexpr int NT = NC / 32;
  __shared__ ushort_t As[32 * KT];
  __shared__ ushort_t Bs[NC * KT];
  const int tid = threadIdx.x;
  const int wv = tid >> 6;
  const int lane = tid & 63;
  const int ml = lane & 15;
  const int quad = lane >> 4;
  const int row0 = blockIdx.x * 32;
  const int mrow = (wv & 1) * 16 + ml;
  const int ncol0 = (wv >> 1) * (NC / 2);
  const bool aF32 = (A_MODE == 0) && (flags[0] != 0);
  f32x4 acc[NT] = {};

  for (int kt = 0; kt < K; kt += KT) {
    for (int c = tid; c < 32 * KT / 8; c += 256) {
      int r = c >> 2, cq = c & 3;
      ushort8 o;
      if (row0 + r < M) {
        if (aF32) {
          const float* ap = (const float*)A + (size_t)(row0 + r) * K + kt + cq * 8;
          float4 f0 = *(const float4*)ap;
          float4 f1 = *(const float4*)(ap + 4);
          o[0] = f2bf(f0.x); o[1] = f2bf(f0.y); o[2] = f2bf(f0.z); o[3] = f2bf(f0.w);
          o[4] = f2bf(f1.x); o[5] = f2bf(f1.y); o[6] = f2bf(f1.z); o[7] = f2bf(f1.w);
        } else {
          o = *(const ushort8*)((const ushort_t*)A + (size_t)(row0 + r) * K + kt + cq * 8);
        }
      } else {
        o = (ushort8)0;
      }
      *(ushort8*)&As[c * 8] = o;
    }
    for (int c = tid; c < NC * KT / 8; c += 256) {
      int n = c >> 2, cq = c & 3;
      *(ushort8*)&Bs[c * 8] = *(const ushort8*)(Bt + (size_t)n * K + kt + cq * 8);
    }
    __syncthreads();
    short8 af = *(const short8*)&As[mrow * KT + quad * 8];
#pragma unroll
    for (int t = 0; t < NT; ++t) {
      short8 bf = *(const short8*)&Bs[(ncol0 + t * 16 + ml) * KT + quad * 8];
      acc[t] = __builtin_amdgcn_mfma_f32_16x16x32_bf16(af, bf, acc[t], 0, 0, 0);
    }
    __syncthreads();
  }

  const int orow = row0 + (wv & 1) * 16 + quad * 4;
#pragma unroll
  for (int t = 0; t < NT; ++t) {
    int col = ncol0 + t * 16 + ml;
#pragma unroll
    for (int r = 0; r < 4; ++r) {
      if (orow + r < M)
        C[(size_t)(orow + r) * NC + col] = f2bf(acc[t][r]);
    }
  }
}

// ---------------- aggregation: one wave per node, bf16 h, norm on the fly ----------------
// (R7's proven form: 30000 waves of TLP, 4-deep unrolled gathers.)

__global__ void aggregate_relu_kernel(const ushort_t* __restrict__ h,
                                      const int* __restrict__ row_ptr,
                                      const int* __restrict__ csr_src,
                                      const float* __restrict__ dinv,
                                      const void* __restrict__ bias,
                                      ushort_t* __restrict__ outp, int n,
                                      const int* __restrict__ flags) {
  int wave = threadIdx.x >> 6;
  int lane = threadIdx.x & 63;
  int v = blockIdx.x * (blockDim.x >> 6) + wave;
  if (v >= n) return;
  float di = dinv[v];
  float sl = di * di;
  ushort2 hv = ((const ushort2*)(h + (size_t)v * GCN_HID))[lane];
  float accx = sl * bf2f(hv.x);
  float accy = sl * bf2f(hv.y);
  int beg = row_ptr[v], end = row_ptr[v + 1];
  for (int base = beg; base < end; base += 64) {
    int cnt = end - base; if (cnt > 64) cnt = 64;
    int sv = 0; float dv = 0.f;
    if (base + lane < end) { sv = csr_src[base + lane]; dv = dinv[sv]; }
    int j = 0;
    for (; j + 4 <= cnt; j += 4) {
      int s0 = __shfl(sv, j), s1 = __shfl(sv, j + 1);
      int s2 = __shfl(sv, j + 2), s3 = __shfl(sv, j + 3);
      float n0 = di * __shfl(dv, j), n1 = di * __shfl(dv, j + 1);
      float n2 = di * __shfl(dv, j + 2), n3 = di * __shfl(dv, j + 3);
      ushort2 g0 = ((const ushort2*)(h + (size_t)s0 * GCN_HID))[lane];
      ushort2 g1 = ((const ushort2*)(h + (size_t)s1 * GCN_HID))[lane];
      ushort2 g2 = ((const ushort2*)(h + (size_t)s2 * GCN_HID))[lane];
      ushort2 g3 = ((const ushort2*)(h + (size_t)s3 * GCN_HID))[lane];
      accx = fmaf(n0, bf2f(g0.x), accx); accy = fmaf(n0, bf2f(g0.y), accy);
      accx = fmaf(n1, bf2f(g1.x), accx); accy = fmaf(n1, bf2f(g1.y), accy);
      accx = fmaf(n2, bf2f(g2.x), accx); accy = fmaf(n2, bf2f(g2.y), accy);
      accx = fmaf(n3, bf2f(g3.x), accx); accy = fmaf(n3, bf2f(g3.y), accy);
    }
    for (; j < cnt; ++j) {
      int s = __shfl(sv, j);
      float nrm = di * __shfl(dv, j);
      ushort2 g = ((const ushort2*)(h + (size_t)s * GCN_HID))[lane];
      accx = fmaf(nrm, bf2f(g.x), accx);
      accy = fmaf(nrm, bf2f(g.y), accy);
    }
  }
  if (flags[0]) {
    accx += ((const float*)bias)[2 * lane];
    accy += ((const float*)bias)[2 * lane + 1];
  } else {
    accx += bf2f(((const ushort_t*)bias)[2 * lane]);
    accy += bf2f(((const ushort_t*)bias)[2 * lane + 1]);
  }
  accx = fmaxf(accx, 0.f);
  accy = fmaxf(accy, 0.f);
  ushort2 o; o.x = f2bf(accx); o.y = f2bf(accy);
  ((ushort2*)(outp + (size_t)v * GCN_HID))[lane] = o;
}

__global__ void aggregate_out_kernel(const ushort_t* __restrict__ h,
                                     const int* __restrict__ row_ptr,
                                     const int* __restrict__ csr_src,
                                     const float* __restrict__ dinv,
                                     const void* __restrict__ bias,
                                     void* __restrict__ outp, int n,
                                     const int* __restrict__ flags) {
  int wave = threadIdx.x >> 6;
  int lane = threadIdx.x & 63;
  int v = blockIdx.x * (blockDim.x >> 6) + wave;
  if (v >= n) return;
  float di = dinv[v];
  float acc = di * di * bf2f(h[(size_t)v * GCN_OUT + lane]);
  int beg = row_ptr[v], end = row_ptr[v + 1];
  for (int base = beg; base < end; base += 64) {
    int cnt = end - base; if (cnt > 64) cnt = 64;
    int sv = 0; float dv = 0.f;
    if (base + lane < end) { sv = csr_src[base + lane]; dv = dinv[sv]; }
    int j = 0;
    for (; j + 4 <= cnt; j += 4) {
      int s0 = __shfl(sv, j), s1 = __shfl(sv, j + 1);
      int s2 = __shfl(sv, j + 2), s3 = __shfl(sv, j + 3);
      float n0 = di * __shfl(dv, j), n1 = di * __shfl(dv, j + 1);
      float n2 = di * __shfl(dv, j + 2), n3 = di * __shfl(dv, j + 3);
      float g0 = bf2f(h[(size_t)s0 * GCN_OUT + lane]);
      float g1 = bf2f(h[(size_t)s1 * GCN_OUT + lane]);
      float g2 = bf2f(h[(size_t)s2 * GCN_OUT + lane]);
      float g3 = bf2f(h[(size_t)s3 * GCN_OUT + lane]);
      acc = fmaf(n0, g0, acc);
      acc = fmaf(n1, g1, acc);
      acc = fmaf(n2, g2, acc);
      acc = fmaf(n3, g3, acc);
    }
    for (; j < cnt; ++j) {
      int s = __shfl(sv, j);
      float nrm = di * __shfl(dv, j);
      acc = fmaf(nrm, bf2f(h[(size_t)s * GCN_OUT + lane]), acc);
    }
  }
  acc += flags[0] ? ((const float*)bias)[lane]
                  : bf2f(((const ushort_t*)bias)[lane]);
  if (flags[0]) ((float*)outp)[(size_t)v * GCN_OUT + lane] = acc;
  else          ((ushort_t*)outp)[(size_t)v * GCN_OUT + lane] = f2bf(acc);
}

// ---------------- launch ----------------

extern "C" void kernel_launch(void* const* d_in, const int* in_sizes, int n_in,
                              void* d_out, int out_size, void* d_ws, size_t ws_size,
                              hipStream_t stream) {
  const void* x  = d_in[0];               // [N, 256] f32 (probed)
  const int*  ei = (const int*)d_in[1];   // [2, E] int32/int64 (probed)
  const void* W1 = d_in[2];               // [256,128]
  const void* b1 = d_in[3];               // [128]
  const void* W2 = d_in[4];               // [128,64]
  const void* b2 = d_in[5];               // [64]

  const int N = in_sizes[0] / GCN_IN;     // 30000
  const int E = in_sizes[1] / 2;          // 600000
  const int nsb  = (E + SBE - 1) / SBE;   // 37 superblocks
  const int nbin = (N + BKT - 1) / BKT;   // 235 buckets (<=256 for LDS hist)

  size_t off = 0;
  auto alloc = [&](size_t bytes) -> void* {
    void* p = (char*)d_ws + off;
    off += (bytes + 255) & ~(size_t)255;
    return p;
  };
  int*          flags   = (int*)alloc(256);
  int*          Hmat    = (int*)alloc((size_t)nbin * nsb * 4);
  unsigned int* stage   = (unsigned int*)alloc((size_t)E * 4);
  int*          csr_src = (int*)alloc((size_t)E * 4);
  int*          row_ptr = (int*)alloc((size_t)(N + 1) * 4);
  float*        dinv    = (float*)alloc((size_t)N * 4);
  ushort_t*     h1      = (ushort_t*)alloc((size_t)N * GCN_HID * 2);  // bf16
  ushort_t*     hag     = (ushort_t*)alloc((size_t)N * GCN_HID * 2);  // bf16
  ushort_t*     wt1     = (ushort_t*)alloc((size_t)GCN_HID * GCN_IN * 2);
  ushort_t*     wt2     = (ushort_t*)alloc((size_t)GCN_OUT * GCN_HID * 2);
  ushort_t*     h2      = h1;  // h1 dead after hag; reuse for GEMM2 output

  probe_kernel<<<1, 64, 0, stream>>>((const ushort_t*)x, ei, flags);
  hist_kernel<<<nsb, 256, 0, stream>>>(ei, E, Hmat, nsb, nbin, flags);
  hscan_kernel<<<1, 1024, 0, stream>>>(Hmat, nbin * nsb);
  stage2_kernel<<<nsb, 256, 0, stream>>>(ei, E, Hmat, nsb, nbin, stage, flags);
  scatter_kernel<<<nbin, 256, 0, stream>>>(stage, Hmat, nsb, nbin, csr_src,
                                           row_ptr, dinv, N, E);

  prep_w_kernel<<<(GCN_IN * GCN_HID + GCN_HID * GCN_OUT + 255) / 256, 256, 0, stream>>>(
      W1, W2, wt1, wt2, flags);

  // GEMM1: [N,256] @ [256,128] -> h1 bf16 (MFMA)
  gemm_mfma_kernel<GCN_IN, GCN_HID, 0>
      <<<(N + 31) / 32, 256, 0, stream>>>(x, wt1, h1, N, flags);

  int gAgg = (N + 3) / 4;  // 4 waves (nodes) per 256-thread block
  aggregate_relu_kernel<<<gAgg, 256, 0, stream>>>(h1, row_ptr, csr_src,
                                                  dinv, b1, hag, N, flags);

  // GEMM2: [N,128] @ [128,64] -> h2 bf16 (MFMA, A bf16)
  gemm_mfma_kernel<GCN_HID, GCN_OUT, 2>
      <<<(N + 31) / 32, 256, 0, stream>>>(hag, wt2, h2, N, flags);

  aggregate_out_kernel<<<gAgg, 256, 0, stream>>>(h2, row_ptr, csr_src,
                                                 dinv, b2, d_out, N, flags);
}